// Round 1
// baseline (3430.562 us; speedup 1.0000x reference)
//
#include <hip/hip_runtime.h>
#include <math.h>

#define NN 200000
#define NE 6400000
#define DIM 128
#define NG 2048
#define NC 10
#define BN_EPS 1e-5f

__device__ __forceinline__ float elu_f(float x) { return x > 0.f ? x : (expf(x) - 1.f); }

// monotonic float<->uint mapping for atomicMax on floats
__device__ __forceinline__ unsigned enc_f(float f) {
    unsigned u = __float_as_uint(f);
    return (u & 0x80000000u) ? ~u : (u | 0x80000000u);
}
__device__ __forceinline__ float dec_f(unsigned k) {
    unsigned u = (k & 0x80000000u) ? (k & 0x7FFFFFFFu) : ~k;
    return __uint_as_float(u);
}

// ---------------- CSR build ----------------

__global__ void hist_kernel(const int* __restrict__ dst, int* __restrict__ counts) {
    int i = blockIdx.x * blockDim.x + threadIdx.x;
    int stride = gridDim.x * blockDim.x;
    for (; i < NE; i += stride) atomicAdd(&counts[dst[i]], 1);
}

__global__ __launch_bounds__(1024) void scan_block_kernel(const int* __restrict__ counts,
                                                          int* __restrict__ offs,
                                                          int* __restrict__ bsum) {
    __shared__ int sdat[1024];
    const int t = threadIdx.x;
    const int i = blockIdx.x * 1024 + t;
    int v = (i < NN) ? counts[i] : 0;
    sdat[t] = v;
    __syncthreads();
    for (int o = 1; o < 1024; o <<= 1) {
        int a = (t >= o) ? sdat[t - o] : 0;
        __syncthreads();
        sdat[t] += a;
        __syncthreads();
    }
    if (i < NN) offs[i] = sdat[t] - v;  // exclusive within block
    if (t == 1023) bsum[blockIdx.x] = sdat[t];
}

__global__ void scan_bsum_kernel(const int* __restrict__ bsum, int* __restrict__ bscan,
                                 int nb, int* __restrict__ offs) {
    if (threadIdx.x == 0 && blockIdx.x == 0) {
        int acc = 0;
        for (int b = 0; b < nb; ++b) { bscan[b] = acc; acc += bsum[b]; }
        offs[NN] = NE;
    }
}

__global__ void add_bscan_kernel(int* __restrict__ offs, const int* __restrict__ bscan,
                                 int* __restrict__ cursor) {
    int i = blockIdx.x * blockDim.x + threadIdx.x;
    if (i < NN) {
        int o = offs[i] + bscan[i >> 10];
        offs[i] = o;
        cursor[i] = o;
    }
}

__global__ void fill_kernel(const int* __restrict__ src, const int* __restrict__ dst,
                            int* __restrict__ cursor, int* __restrict__ csr) {
    int i = blockIdx.x * blockDim.x + threadIdx.x;
    int stride = gridDim.x * blockDim.x;
    for (; i < NE; i += stride) {
        int p = atomicAdd(&cursor[dst[i]], 1);
        csr[p] = src[i];
    }
}

// ---------------- BN fold: W1f[:,c] = W1[:,c]*s_c*gamma_c ; b1f folded ----------------

__global__ void fold_kernel(const float* __restrict__ W1, const float* __restrict__ b1,
                            const float* __restrict__ gamma, const float* __restrict__ beta,
                            const float* __restrict__ rm, const float* __restrict__ rv,
                            float* __restrict__ W1f, float* __restrict__ b1f) {
    int idx = blockIdx.x * blockDim.x + threadIdx.x;
    if (idx < DIM * DIM) {
        int c = idx & (DIM - 1);
        float sc = rsqrtf(rv[c] + BN_EPS) * gamma[c];
        W1f[idx] = W1[idx] * sc;
        if (idx < DIM) {
            float s2 = rsqrtf(rv[idx] + BN_EPS) * gamma[idx];
            b1f[idx] = (b1[idx] - rm[idx]) * s2 + beta[idx];
        }
    }
}

// ---------------- fused GIN layer: aggregate + MLP (+optional pool) ----------------

__device__ __forceinline__ void gemm_tile(const float (*tile)[DIM + 1], int node, int c0,
                                          const float* __restrict__ W, const float* __restrict__ b,
                                          float r[32]) {
#pragma unroll
    for (int c = 0; c < 32; ++c) r[c] = b[c0 + c];
    const float4* W4 = reinterpret_cast<const float4*>(W);
    for (int k = 0; k < DIM; ++k) {
        const float a = tile[node][k];
        const float4* wr = W4 + k * (DIM / 4) + (c0 >> 2);
#pragma unroll
        for (int q = 0; q < 8; ++q) {
            float4 w = wr[q];
            r[q * 4 + 0] += a * w.x;
            r[q * 4 + 1] += a * w.y;
            r[q * 4 + 2] += a * w.z;
            r[q * 4 + 3] += a * w.w;
        }
    }
}

template <int POOL>
__global__ __launch_bounds__(256) void gin_layer_kernel(
    const float* __restrict__ fin, const int* __restrict__ offs, const int* __restrict__ csr,
    const float* __restrict__ W1f, const float* __restrict__ b1f,
    const float* __restrict__ W2, const float* __restrict__ b2,
    float* __restrict__ hout, unsigned int* __restrict__ gkey, const int* __restrict__ batch) {
    __shared__ float tile[64][DIM + 1];   // stride 129: conflict-free column reads
    __shared__ int batch_s[64];

    const int base = blockIdx.x * 64;
    const int t = threadIdx.x;
    const int lane = t & 63;
    const int wave = t >> 6;

    if (POOL && t < 64) batch_s[t] = batch[base + t];

    // ---- aggregation: acc = x[n] + sum_{s in CSR[n]} x[s], lane holds 2 features ----
    for (int i = wave; i < 64; i += 4) {
        const int n = base + i;
        const float2* own = reinterpret_cast<const float2*>(fin + (size_t)n * DIM);
        float2 acc = own[lane];
        const int e0 = offs[n];
        const int e1 = offs[n + 1];
        int e = e0;
        for (; e + 4 <= e1; e += 4) {  // 4-deep ILP on the random gathers
            int s0 = csr[e], s1 = csr[e + 1], s2 = csr[e + 2], s3 = csr[e + 3];
            float2 v0 = reinterpret_cast<const float2*>(fin + (size_t)s0 * DIM)[lane];
            float2 v1 = reinterpret_cast<const float2*>(fin + (size_t)s1 * DIM)[lane];
            float2 v2 = reinterpret_cast<const float2*>(fin + (size_t)s2 * DIM)[lane];
            float2 v3 = reinterpret_cast<const float2*>(fin + (size_t)s3 * DIM)[lane];
            acc.x += v0.x + v1.x + v2.x + v3.x;
            acc.y += v0.y + v1.y + v2.y + v3.y;
        }
        for (; e < e1; ++e) {
            int s = csr[e];
            float2 v = reinterpret_cast<const float2*>(fin + (size_t)s * DIM)[lane];
            acc.x += v.x;
            acc.y += v.y;
        }
        tile[i][2 * lane] = acc.x;
        tile[i][2 * lane + 1] = acc.y;
    }
    __syncthreads();

    const int node = t & 63;
    const int c0 = (t >> 6) * 32;
    float r[32];

    // ---- GEMM1 (BN folded) + ELU ----
    gemm_tile(tile, node, c0, W1f, b1f, r);
#pragma unroll
    for (int c = 0; c < 32; ++c) r[c] = elu_f(r[c]);
    __syncthreads();  // all tile reads done
#pragma unroll
    for (int c = 0; c < 32; ++c) tile[node][c0 + c] = r[c];
    __syncthreads();

    // ---- GEMM2 + ELU ----
    gemm_tile(tile, node, c0, W2, b2, r);
#pragma unroll
    for (int c = 0; c < 32; ++c) r[c] = elu_f(r[c]);
    __syncthreads();
#pragma unroll
    for (int c = 0; c < 32; ++c) tile[node][c0 + c] = r[c];
    __syncthreads();

    if (!POOL) {
        // coalesced write of h
        for (int idx = t; idx < 64 * DIM; idx += 256) {
            int n = idx >> 7, c = idx & (DIM - 1);
            hout[(size_t)(base + n) * DIM + c] = tile[n][c];
        }
    } else {
        // per-block partial max per graph segment, then one atomic per (graph,col)
        if (t < DIM) {
            const int col = t;
            const int g0 = batch_s[0], g1 = batch_s[63];
            for (int g = g0; g <= g1; ++g) {
                float m = -INFINITY;
                bool any = false;
                for (int i = 0; i < 64; ++i) {
                    if (batch_s[i] == g) { m = fmaxf(m, tile[i][col]); any = true; }
                }
                if (any) atomicMax(&gkey[(size_t)g * DIM + col], enc_f(m));
            }
        }
    }
}

// ---------------- head: g -> elu(g@W+b) -> @W2+b2 -> softmax ----------------

__global__ __launch_bounds__(128) void head_kernel(const unsigned int* __restrict__ gkey,
                                                   const float* __restrict__ l1W,
                                                   const float* __restrict__ l1b,
                                                   const float* __restrict__ l2W,
                                                   const float* __restrict__ l2b,
                                                   float* __restrict__ out) {
    __shared__ float gv[DIM];
    __shared__ float y1[DIM];
    __shared__ float lg[NC];
    const int g = blockIdx.x;
    const int t = threadIdx.x;
    gv[t] = dec_f(gkey[(size_t)g * DIM + t]);
    __syncthreads();
    float s = l1b[t];
    for (int k = 0; k < DIM; ++k) s += gv[k] * l1W[k * DIM + t];
    y1[t] = elu_f(s);
    __syncthreads();
    if (t < NC) {
        float s2 = l2b[t];
        for (int k = 0; k < DIM; ++k) s2 += y1[k] * l2W[k * NC + t];
        lg[t] = s2;
    }
    __syncthreads();
    if (t == 0) {
        float m = -INFINITY;
        for (int j = 0; j < NC; ++j) m = fmaxf(m, lg[j]);
        float e[NC];
        float sum = 0.f;
        for (int j = 0; j < NC; ++j) { e[j] = expf(lg[j] - m); sum += e[j]; }
        float inv = 1.f / sum;
        for (int j = 0; j < NC; ++j) out[(size_t)g * NC + j] = e[j] * inv;
    }
}

// ---------------- launch ----------------

extern "C" void kernel_launch(void* const* d_in, const int* in_sizes, int n_in,
                              void* d_out, int out_size, void* d_ws, size_t ws_size,
                              hipStream_t stream) {
    (void)in_sizes; (void)n_in; (void)out_size; (void)ws_size;
    const float* x     = (const float*)d_in[0];
    const int*   edge  = (const int*)d_in[1];
    const int*   batch = (const int*)d_in[2];
    const float* c1_W1 = (const float*)d_in[3];
    const float* c1_b1 = (const float*)d_in[4];
    const float* c1_g  = (const float*)d_in[5];
    const float* c1_be = (const float*)d_in[6];
    const float* c1_rm = (const float*)d_in[7];
    const float* c1_rv = (const float*)d_in[8];
    const float* c1_W2 = (const float*)d_in[9];
    const float* c1_b2 = (const float*)d_in[10];
    const float* c2_W1 = (const float*)d_in[11];
    const float* c2_b1 = (const float*)d_in[12];
    const float* c2_g  = (const float*)d_in[13];
    const float* c2_be = (const float*)d_in[14];
    const float* c2_rm = (const float*)d_in[15];
    const float* c2_rv = (const float*)d_in[16];
    const float* c2_W2 = (const float*)d_in[17];
    const float* c2_b2 = (const float*)d_in[18];
    const float* l1_W  = (const float*)d_in[19];
    const float* l1_b  = (const float*)d_in[20];
    const float* l2_W  = (const float*)d_in[21];
    const float* l2_b  = (const float*)d_in[22];
    float* out = (float*)d_out;

    char* wsb = (char*)d_ws;
    size_t off = 0;
    auto take = [&](size_t bytes) -> char* {
        char* p = wsb + off;
        off += (bytes + 255) & ~(size_t)255;
        return p;
    };
    int* counts    = (int*)take((size_t)NN * 4);
    int* offs      = (int*)take((size_t)(NN + 1) * 4);
    int* cursor    = (int*)take((size_t)NN * 4);
    int* bsum      = (int*)take(256 * 4);
    int* bscan     = (int*)take(256 * 4);
    int* csr       = (int*)take((size_t)NE * 4);
    float* h1      = (float*)take((size_t)NN * DIM * 4);
    unsigned* gkey = (unsigned*)take((size_t)NG * DIM * 4);
    float* W1f_a   = (float*)take((size_t)DIM * DIM * 4);
    float* b1f_a   = (float*)take((size_t)DIM * 4);
    float* W1f_b   = (float*)take((size_t)DIM * DIM * 4);
    float* b1f_b   = (float*)take((size_t)DIM * 4);

    const int* esrc = edge;
    const int* edst = edge + NE;

    hipMemsetAsync(counts, 0, (size_t)NN * 4, stream);
    hipMemsetAsync(gkey, 0, (size_t)NG * DIM * 4, stream);

    fold_kernel<<<64, 256, 0, stream>>>(c1_W1, c1_b1, c1_g, c1_be, c1_rm, c1_rv, W1f_a, b1f_a);
    fold_kernel<<<64, 256, 0, stream>>>(c2_W1, c2_b1, c2_g, c2_be, c2_rm, c2_rv, W1f_b, b1f_b);

    hist_kernel<<<4096, 256, 0, stream>>>(edst, counts);
    scan_block_kernel<<<196, 1024, 0, stream>>>(counts, offs, bsum);
    scan_bsum_kernel<<<1, 1, 0, stream>>>(bsum, bscan, 196, offs);
    add_bscan_kernel<<<782, 256, 0, stream>>>(offs, bscan, cursor);
    fill_kernel<<<4096, 256, 0, stream>>>(esrc, edst, cursor, csr);

    gin_layer_kernel<0><<<NN / 64, 256, 0, stream>>>(x, offs, csr, W1f_a, b1f_a, c1_W2, c1_b2,
                                                     h1, nullptr, nullptr);
    gin_layer_kernel<1><<<NN / 64, 256, 0, stream>>>(h1, offs, csr, W1f_b, b1f_b, c2_W2, c2_b2,
                                                     nullptr, gkey, batch);

    head_kernel<<<NG, 128, 0, stream>>>(gkey, l1_W, l1_b, l2_W, l2_b, out);
}

// Round 2
// 3106.388 us; speedup vs baseline: 1.1044x; 1.1044x over previous
//
#include <hip/hip_runtime.h>
#include <hip/hip_fp16.h>
#include <math.h>

#define NN 200000
#define NE 6400000
#define DIM 128
#define NG 2048
#define NC 10
#define BN_EPS 1e-5f

__device__ __forceinline__ float elu_f(float x) { return x > 0.f ? x : (expf(x) - 1.f); }

// monotonic float<->uint mapping for atomicMax on floats
__device__ __forceinline__ unsigned enc_f(float f) {
    unsigned u = __float_as_uint(f);
    return (u & 0x80000000u) ? ~u : (u | 0x80000000u);
}
__device__ __forceinline__ float dec_f(unsigned k) {
    unsigned u = (k & 0x80000000u) ? (k & 0x7FFFFFFFu) : ~k;
    return __uint_as_float(u);
}

// ---------------- fp32 -> fp16 feature conversion ----------------

__global__ void to_half_kernel(const float* __restrict__ in, __half* __restrict__ out, int n2) {
    int i = blockIdx.x * blockDim.x + threadIdx.x;
    int stride = gridDim.x * blockDim.x;
    const float2* in2 = reinterpret_cast<const float2*>(in);
    __half2* out2 = reinterpret_cast<__half2*>(out);
    for (; i < n2; i += stride) out2[i] = __float22half2_rn(in2[i]);
}

// ---------------- CSR build ----------------

__global__ void hist_kernel(const int* __restrict__ dst, int* __restrict__ counts) {
    int i = blockIdx.x * blockDim.x + threadIdx.x;
    int stride = gridDim.x * blockDim.x;
    for (; i < NE; i += stride) atomicAdd(&counts[dst[i]], 1);
}

__global__ __launch_bounds__(1024) void scan_block_kernel(const int* __restrict__ counts,
                                                          int* __restrict__ offs,
                                                          int* __restrict__ bsum) {
    __shared__ int sdat[1024];
    const int t = threadIdx.x;
    const int i = blockIdx.x * 1024 + t;
    int v = (i < NN) ? counts[i] : 0;
    sdat[t] = v;
    __syncthreads();
    for (int o = 1; o < 1024; o <<= 1) {
        int a = (t >= o) ? sdat[t - o] : 0;
        __syncthreads();
        sdat[t] += a;
        __syncthreads();
    }
    if (i < NN) offs[i] = sdat[t] - v;  // exclusive within block
    if (t == 1023) bsum[blockIdx.x] = sdat[t];
}

__global__ void scan_bsum_kernel(const int* __restrict__ bsum, int* __restrict__ bscan,
                                 int nb, int* __restrict__ offs) {
    if (threadIdx.x == 0 && blockIdx.x == 0) {
        int acc = 0;
        for (int b = 0; b < nb; ++b) { bscan[b] = acc; acc += bsum[b]; }
        offs[NN] = NE;
    }
}

__global__ void add_bscan_kernel(int* __restrict__ offs, const int* __restrict__ bscan,
                                 int* __restrict__ cursor) {
    int i = blockIdx.x * blockDim.x + threadIdx.x;
    if (i < NN) {
        int o = offs[i] + bscan[i >> 10];
        offs[i] = o;
        cursor[i] = o;
    }
}

__global__ void fill_kernel(const int* __restrict__ src, const int* __restrict__ dst,
                            int* __restrict__ cursor, int* __restrict__ csr) {
    int i = blockIdx.x * blockDim.x + threadIdx.x;
    int stride = gridDim.x * blockDim.x;
    for (; i < NE; i += stride) {
        int p = atomicAdd(&cursor[dst[i]], 1);
        csr[p] = src[i];
    }
}

// ---------------- BN fold ----------------

__global__ void fold_kernel(const float* __restrict__ W1, const float* __restrict__ b1,
                            const float* __restrict__ gamma, const float* __restrict__ beta,
                            const float* __restrict__ rm, const float* __restrict__ rv,
                            float* __restrict__ W1f, float* __restrict__ b1f) {
    int idx = blockIdx.x * blockDim.x + threadIdx.x;
    if (idx < DIM * DIM) {
        int c = idx & (DIM - 1);
        float sc = rsqrtf(rv[c] + BN_EPS) * gamma[c];
        W1f[idx] = W1[idx] * sc;
        if (idx < DIM) {
            float s2 = rsqrtf(rv[idx] + BN_EPS) * gamma[idx];
            b1f[idx] = (b1[idx] - rm[idx]) * s2 + beta[idx];
        }
    }
}

// ---------------- fused GIN layer: fp16 gather + fp32 MLP (+optional pool) ----------------

__device__ __forceinline__ void gemm_tile(const float (*tile)[DIM + 1], int node, int c0,
                                          const float* __restrict__ W, const float* __restrict__ b,
                                          float r[32]) {
#pragma unroll
    for (int c = 0; c < 32; ++c) r[c] = b[c0 + c];
    const float4* W4 = reinterpret_cast<const float4*>(W);
    for (int k = 0; k < DIM; ++k) {
        const float a = tile[node][k];
        const float4* wr = W4 + k * (DIM / 4) + (c0 >> 2);
#pragma unroll
        for (int q = 0; q < 8; ++q) {
            float4 w = wr[q];
            r[q * 4 + 0] += a * w.x;
            r[q * 4 + 1] += a * w.y;
            r[q * 4 + 2] += a * w.z;
            r[q * 4 + 3] += a * w.w;
        }
    }
}

template <int POOL>
__global__ __launch_bounds__(256) void gin_layer_kernel(
    const __half* __restrict__ fin, const int* __restrict__ offs, const int* __restrict__ csr,
    const float* __restrict__ W1f, const float* __restrict__ b1f,
    const float* __restrict__ W2, const float* __restrict__ b2,
    __half* __restrict__ hout, unsigned int* __restrict__ gkey, const int* __restrict__ batch) {
    __shared__ float tile[64][DIM + 1];   // stride 129: conflict-free column reads
    __shared__ int batch_s[64];

    const int base = blockIdx.x * 64;
    const int t = threadIdx.x;
    const int lane = t & 63;
    const int wave = t >> 6;

    if (POOL && t < 64) batch_s[t] = batch[base + t];

    const __half2* fin2 = reinterpret_cast<const __half2*>(fin);  // row = 64 half2

    // ---- aggregation: acc = x[n] + sum_{s in CSR[n]} x[s]; lane holds 2 features ----
    for (int i = wave; i < 64; i += 4) {
        const int n = base + i;
        float2 f0 = __half22float2(fin2[(size_t)n * 64 + lane]);
        float2 acc = f0;
        const int e0 = offs[n];
        const int e1 = offs[n + 1];
        int e = e0;
        for (; e + 8 <= e1; e += 8) {  // 8-deep ILP on the random gathers
            int s0 = csr[e + 0], s1 = csr[e + 1], s2 = csr[e + 2], s3 = csr[e + 3];
            int s4 = csr[e + 4], s5 = csr[e + 5], s6 = csr[e + 6], s7 = csr[e + 7];
            __half2 v0 = fin2[(size_t)s0 * 64 + lane];
            __half2 v1 = fin2[(size_t)s1 * 64 + lane];
            __half2 v2 = fin2[(size_t)s2 * 64 + lane];
            __half2 v3 = fin2[(size_t)s3 * 64 + lane];
            __half2 v4 = fin2[(size_t)s4 * 64 + lane];
            __half2 v5 = fin2[(size_t)s5 * 64 + lane];
            __half2 v6 = fin2[(size_t)s6 * 64 + lane];
            __half2 v7 = fin2[(size_t)s7 * 64 + lane];
            float2 f;
            f = __half22float2(v0); acc.x += f.x; acc.y += f.y;
            f = __half22float2(v1); acc.x += f.x; acc.y += f.y;
            f = __half22float2(v2); acc.x += f.x; acc.y += f.y;
            f = __half22float2(v3); acc.x += f.x; acc.y += f.y;
            f = __half22float2(v4); acc.x += f.x; acc.y += f.y;
            f = __half22float2(v5); acc.x += f.x; acc.y += f.y;
            f = __half22float2(v6); acc.x += f.x; acc.y += f.y;
            f = __half22float2(v7); acc.x += f.x; acc.y += f.y;
        }
        for (; e < e1; ++e) {
            int s = csr[e];
            float2 f = __half22float2(fin2[(size_t)s * 64 + lane]);
            acc.x += f.x;
            acc.y += f.y;
        }
        tile[i][2 * lane] = acc.x;
        tile[i][2 * lane + 1] = acc.y;
    }
    __syncthreads();

    const int node = t & 63;
    const int c0 = (t >> 6) * 32;
    float r[32];

    // ---- GEMM1 (BN folded) + ELU ----
    gemm_tile(tile, node, c0, W1f, b1f, r);
#pragma unroll
    for (int c = 0; c < 32; ++c) r[c] = elu_f(r[c]);
    __syncthreads();
#pragma unroll
    for (int c = 0; c < 32; ++c) tile[node][c0 + c] = r[c];
    __syncthreads();

    // ---- GEMM2 + ELU ----
    gemm_tile(tile, node, c0, W2, b2, r);
#pragma unroll
    for (int c = 0; c < 32; ++c) r[c] = elu_f(r[c]);
    __syncthreads();
#pragma unroll
    for (int c = 0; c < 32; ++c) tile[node][c0 + c] = r[c];
    __syncthreads();

    if (!POOL) {
        // coalesced fp16 write of h: two rows (2x256B) per wave-iteration
        __half2* hout2 = reinterpret_cast<__half2*>(hout);
        for (int idx = t; idx < 64 * 64; idx += 256) {
            int n = idx >> 6, c2 = idx & 63;
            float2 f;
            f.x = tile[n][2 * c2];
            f.y = tile[n][2 * c2 + 1];
            hout2[(size_t)(base + n) * 64 + c2] = __float22half2_rn(f);
        }
    } else {
        // per-block partial max per graph segment, then one atomic per (graph,col)
        if (t < DIM) {
            const int col = t;
            const int g0 = batch_s[0], g1 = batch_s[63];
            for (int g = g0; g <= g1; ++g) {
                float m = -INFINITY;
                bool any = false;
                for (int i = 0; i < 64; ++i) {
                    if (batch_s[i] == g) { m = fmaxf(m, tile[i][col]); any = true; }
                }
                if (any) atomicMax(&gkey[(size_t)g * DIM + col], enc_f(m));
            }
        }
    }
}

// ---------------- head ----------------

__global__ __launch_bounds__(128) void head_kernel(const unsigned int* __restrict__ gkey,
                                                   const float* __restrict__ l1W,
                                                   const float* __restrict__ l1b,
                                                   const float* __restrict__ l2W,
                                                   const float* __restrict__ l2b,
                                                   float* __restrict__ out) {
    __shared__ float gv[DIM];
    __shared__ float y1[DIM];
    __shared__ float lg[NC];
    const int g = blockIdx.x;
    const int t = threadIdx.x;
    gv[t] = dec_f(gkey[(size_t)g * DIM + t]);
    __syncthreads();
    float s = l1b[t];
    for (int k = 0; k < DIM; ++k) s += gv[k] * l1W[k * DIM + t];
    y1[t] = elu_f(s);
    __syncthreads();
    if (t < NC) {
        float s2 = l2b[t];
        for (int k = 0; k < DIM; ++k) s2 += y1[k] * l2W[k * NC + t];
        lg[t] = s2;
    }
    __syncthreads();
    if (t == 0) {
        float m = -INFINITY;
        for (int j = 0; j < NC; ++j) m = fmaxf(m, lg[j]);
        float e[NC];
        float sum = 0.f;
        for (int j = 0; j < NC; ++j) { e[j] = expf(lg[j] - m); sum += e[j]; }
        float inv = 1.f / sum;
        for (int j = 0; j < NC; ++j) out[(size_t)g * NC + j] = e[j] * inv;
    }
}

// ---------------- launch ----------------

extern "C" void kernel_launch(void* const* d_in, const int* in_sizes, int n_in,
                              void* d_out, int out_size, void* d_ws, size_t ws_size,
                              hipStream_t stream) {
    (void)in_sizes; (void)n_in; (void)out_size; (void)ws_size;
    const float* x     = (const float*)d_in[0];
    const int*   edge  = (const int*)d_in[1];
    const int*   batch = (const int*)d_in[2];
    const float* c1_W1 = (const float*)d_in[3];
    const float* c1_b1 = (const float*)d_in[4];
    const float* c1_g  = (const float*)d_in[5];
    const float* c1_be = (const float*)d_in[6];
    const float* c1_rm = (const float*)d_in[7];
    const float* c1_rv = (const float*)d_in[8];
    const float* c1_W2 = (const float*)d_in[9];
    const float* c1_b2 = (const float*)d_in[10];
    const float* c2_W1 = (const float*)d_in[11];
    const float* c2_b1 = (const float*)d_in[12];
    const float* c2_g  = (const float*)d_in[13];
    const float* c2_be = (const float*)d_in[14];
    const float* c2_rm = (const float*)d_in[15];
    const float* c2_rv = (const float*)d_in[16];
    const float* c2_W2 = (const float*)d_in[17];
    const float* c2_b2 = (const float*)d_in[18];
    const float* l1_W  = (const float*)d_in[19];
    const float* l1_b  = (const float*)d_in[20];
    const float* l2_W  = (const float*)d_in[21];
    const float* l2_b  = (const float*)d_in[22];
    float* out = (float*)d_out;

    char* wsb = (char*)d_ws;
    size_t off = 0;
    auto take = [&](size_t bytes) -> char* {
        char* p = wsb + off;
        off += (bytes + 255) & ~(size_t)255;
        return p;
    };
    int* counts    = (int*)take((size_t)NN * 4);
    int* offs      = (int*)take((size_t)(NN + 1) * 4);
    int* cursor    = (int*)take((size_t)NN * 4);
    int* bsum      = (int*)take(256 * 4);
    int* bscan     = (int*)take(256 * 4);
    int* csr       = (int*)take((size_t)NE * 4);
    __half* xh     = (__half*)take((size_t)NN * DIM * 2);
    __half* h1h    = (__half*)take((size_t)NN * DIM * 2);
    unsigned* gkey = (unsigned*)take((size_t)NG * DIM * 4);
    float* W1f_a   = (float*)take((size_t)DIM * DIM * 4);
    float* b1f_a   = (float*)take((size_t)DIM * 4);
    float* W1f_b   = (float*)take((size_t)DIM * DIM * 4);
    float* b1f_b   = (float*)take((size_t)DIM * 4);

    const int* esrc = edge;
    const int* edst = edge + NE;

    hipMemsetAsync(counts, 0, (size_t)NN * 4, stream);
    hipMemsetAsync(gkey, 0, (size_t)NG * DIM * 4, stream);

    fold_kernel<<<64, 256, 0, stream>>>(c1_W1, c1_b1, c1_g, c1_be, c1_rm, c1_rv, W1f_a, b1f_a);
    fold_kernel<<<64, 256, 0, stream>>>(c2_W1, c2_b1, c2_g, c2_be, c2_rm, c2_rv, W1f_b, b1f_b);

    to_half_kernel<<<2048, 256, 0, stream>>>(x, xh, NN * DIM / 2);

    hist_kernel<<<4096, 256, 0, stream>>>(edst, counts);
    scan_block_kernel<<<196, 1024, 0, stream>>>(counts, offs, bsum);
    scan_bsum_kernel<<<1, 1, 0, stream>>>(bsum, bscan, 196, offs);
    add_bscan_kernel<<<782, 256, 0, stream>>>(offs, bscan, cursor);
    fill_kernel<<<4096, 256, 0, stream>>>(esrc, edst, cursor, csr);

    gin_layer_kernel<0><<<NN / 64, 256, 0, stream>>>(xh, offs, csr, W1f_a, b1f_a, c1_W2, c1_b2,
                                                     h1h, nullptr, nullptr);
    gin_layer_kernel<1><<<NN / 64, 256, 0, stream>>>(h1h, offs, csr, W1f_b, b1f_b, c2_W2, c2_b2,
                                                     nullptr, gkey, batch);

    head_kernel<<<NG, 128, 0, stream>>>(gkey, l1_W, l1_b, l2_W, l2_b, out);
}

// Round 3
// 2714.630 us; speedup vs baseline: 1.2637x; 1.1443x over previous
//
#include <hip/hip_runtime.h>
#include <hip/hip_fp16.h>
#include <math.h>

#define NN 200000
#define NE 6400000
#define DIM 128
#define NG 2048
#define NC 10
#define BN_EPS 1e-5f
// padded CSR upper bound: NE + NN*7, rounded up
#define NE_PAD 7800000

__device__ __forceinline__ float elu_f(float x) { return x > 0.f ? x : (expf(x) - 1.f); }

// monotonic float<->uint mapping for atomicMax on floats
__device__ __forceinline__ unsigned enc_f(float f) {
    unsigned u = __float_as_uint(f);
    return (u & 0x80000000u) ? ~u : (u | 0x80000000u);
}
__device__ __forceinline__ float dec_f(unsigned k) {
    unsigned u = (k & 0x80000000u) ? (k & 0x7FFFFFFFu) : ~k;
    return __uint_as_float(u);
}

// ---------------- fp32 -> fp16 feature conversion ----------------

__global__ void to_half_kernel(const float* __restrict__ in, __half* __restrict__ out, int n2) {
    int i = blockIdx.x * blockDim.x + threadIdx.x;
    int stride = gridDim.x * blockDim.x;
    const float2* in2 = reinterpret_cast<const float2*>(in);
    __half2* out2 = reinterpret_cast<__half2*>(out);
    for (; i < n2; i += stride) out2[i] = __float22half2_rn(in2[i]);
}

// ---------------- CSR build (padded to multiples of 8) ----------------

__global__ void hist_kernel(const int* __restrict__ dst, int* __restrict__ counts) {
    int i = blockIdx.x * blockDim.x + threadIdx.x;
    int stride = gridDim.x * blockDim.x;
    for (; i < NE; i += stride) atomicAdd(&counts[dst[i]], 1);
}

__global__ void pad_counts_kernel(int* __restrict__ counts) {
    int i = blockIdx.x * blockDim.x + threadIdx.x;
    if (i < NN) counts[i] = (counts[i] + 7) & ~7;
}

__global__ __launch_bounds__(1024) void scan_block_kernel(const int* __restrict__ counts,
                                                          int* __restrict__ offs,
                                                          int* __restrict__ bsum) {
    __shared__ int sdat[1024];
    const int t = threadIdx.x;
    const int i = blockIdx.x * 1024 + t;
    int v = (i < NN) ? counts[i] : 0;
    sdat[t] = v;
    __syncthreads();
    for (int o = 1; o < 1024; o <<= 1) {
        int a = (t >= o) ? sdat[t - o] : 0;
        __syncthreads();
        sdat[t] += a;
        __syncthreads();
    }
    if (i < NN) offs[i] = sdat[t] - v;  // exclusive within block
    if (t == 1023) bsum[blockIdx.x] = sdat[t];
}

__global__ void scan_bsum_kernel(const int* __restrict__ bsum, int* __restrict__ bscan,
                                 int nb, int* __restrict__ offs) {
    if (threadIdx.x == 0 && blockIdx.x == 0) {
        int acc = 0;
        for (int b = 0; b < nb; ++b) { bscan[b] = acc; acc += bsum[b]; }
        offs[NN] = acc;  // total padded edge count
    }
}

__global__ void add_bscan_kernel(int* __restrict__ offs, const int* __restrict__ bscan,
                                 int* __restrict__ cursor) {
    int i = blockIdx.x * blockDim.x + threadIdx.x;
    if (i < NN) {
        int o = offs[i] + bscan[i >> 10];
        offs[i] = o;
        cursor[i] = o;
    }
}

// init padded csr with the dummy zero-row index NN
__global__ void csr_init_kernel(int* __restrict__ csr) {
    int i = blockIdx.x * blockDim.x + threadIdx.x;
    int stride = gridDim.x * blockDim.x;
    for (; i < NE_PAD; i += stride) csr[i] = NN;
}

__global__ void fill_kernel(const int* __restrict__ src, const int* __restrict__ dst,
                            int* __restrict__ cursor, int* __restrict__ csr) {
    int i = blockIdx.x * blockDim.x + threadIdx.x;
    int stride = gridDim.x * blockDim.x;
    for (; i < NE; i += stride) {
        int p = atomicAdd(&cursor[dst[i]], 1);
        csr[p] = src[i];
    }
}

// ---------------- BN fold ----------------

__global__ void fold_kernel(const float* __restrict__ W1, const float* __restrict__ b1,
                            const float* __restrict__ gamma, const float* __restrict__ beta,
                            const float* __restrict__ rm, const float* __restrict__ rv,
                            float* __restrict__ W1f, float* __restrict__ b1f) {
    int idx = blockIdx.x * blockDim.x + threadIdx.x;
    if (idx < DIM * DIM) {
        int c = idx & (DIM - 1);
        float sc = rsqrtf(rv[c] + BN_EPS) * gamma[c];
        W1f[idx] = W1[idx] * sc;
        if (idx < DIM) {
            float s2 = rsqrtf(rv[idx] + BN_EPS) * gamma[idx];
            b1f[idx] = (b1[idx] - rm[idx]) * s2 + beta[idx];
        }
    }
}

// ---------------- fused GIN layer: fp16 gather + MLP (+optional pool) ----------------

#define TPAD 130  // half stride: 65 dwords -> bank-conflict-free column access

__device__ __forceinline__ void gemm_tile(const __half (*tile)[TPAD], int node, int c0,
                                          const float* __restrict__ W, const float* __restrict__ b,
                                          float r[32]) {
#pragma unroll
    for (int c = 0; c < 32; ++c) r[c] = b[c0 + c];
    const float4* W4 = reinterpret_cast<const float4*>(W);
    for (int k = 0; k < DIM; ++k) {
        const float a = __half2float(tile[node][k]);
        const float4* wr = W4 + k * (DIM / 4) + (c0 >> 2);
#pragma unroll
        for (int q = 0; q < 8; ++q) {
            float4 w = wr[q];
            r[q * 4 + 0] += a * w.x;
            r[q * 4 + 1] += a * w.y;
            r[q * 4 + 2] += a * w.z;
            r[q * 4 + 3] += a * w.w;
        }
    }
}

template <int POOL>
__global__ __launch_bounds__(256) void gin_layer_kernel(
    const __half* __restrict__ fin, const int* __restrict__ offs, const int* __restrict__ csr,
    const float* __restrict__ W1f, const float* __restrict__ b1f,
    const float* __restrict__ W2, const float* __restrict__ b2,
    __half* __restrict__ hout, unsigned int* __restrict__ gkey, const int* __restrict__ batch) {
    __shared__ __half tile[64][TPAD];  // 16.9 KB -> 8 blocks/CU
    __shared__ int batch_s[64];

    const int base = blockIdx.x * 64;
    const int t = threadIdx.x;
    const int lane = t & 63;
    const int wave = t >> 6;

    if (POOL && t < 64) batch_s[t] = batch[base + t];

    const __half2* fin2 = reinterpret_cast<const __half2*>(fin);  // row = 64 half2

    // ---- aggregation: acc = x[n] + sum_{s in CSR[n]} x[s]; lane holds 2 features ----
    for (int i = wave; i < 64; i += 4) {
        const int n = base + i;
        float2 acc = __half22float2(fin2[(size_t)n * 64 + lane]);
        const int e0 = offs[n];
        const int e1 = offs[n + 1];
        // padded: (e1-e0) % 8 == 0, e0 % 8 == 0 -> int4-aligned index loads
        for (int e = e0; e < e1; e += 8) {
            const int4* c4 = reinterpret_cast<const int4*>(csr + e);
            int4 ca = c4[0];
            int4 cb = c4[1];
            __half2 v0 = fin2[(size_t)ca.x * 64 + lane];
            __half2 v1 = fin2[(size_t)ca.y * 64 + lane];
            __half2 v2 = fin2[(size_t)ca.z * 64 + lane];
            __half2 v3 = fin2[(size_t)ca.w * 64 + lane];
            __half2 v4 = fin2[(size_t)cb.x * 64 + lane];
            __half2 v5 = fin2[(size_t)cb.y * 64 + lane];
            __half2 v6 = fin2[(size_t)cb.z * 64 + lane];
            __half2 v7 = fin2[(size_t)cb.w * 64 + lane];
            float2 f;
            f = __half22float2(v0); acc.x += f.x; acc.y += f.y;
            f = __half22float2(v1); acc.x += f.x; acc.y += f.y;
            f = __half22float2(v2); acc.x += f.x; acc.y += f.y;
            f = __half22float2(v3); acc.x += f.x; acc.y += f.y;
            f = __half22float2(v4); acc.x += f.x; acc.y += f.y;
            f = __half22float2(v5); acc.x += f.x; acc.y += f.y;
            f = __half22float2(v6); acc.x += f.x; acc.y += f.y;
            f = __half22float2(v7); acc.x += f.x; acc.y += f.y;
        }
        *reinterpret_cast<__half2*>(&tile[i][2 * lane]) = __float22half2_rn(acc);
    }
    __syncthreads();

    const int node = t & 63;
    const int c0 = (t >> 6) * 32;
    float r[32];

    // ---- GEMM1 (BN folded) + ELU ----
    gemm_tile(tile, node, c0, W1f, b1f, r);
#pragma unroll
    for (int c = 0; c < 32; ++c) r[c] = elu_f(r[c]);
    __syncthreads();
#pragma unroll
    for (int c = 0; c < 32; ++c) tile[node][c0 + c] = __float2half(r[c]);
    __syncthreads();

    // ---- GEMM2 + ELU ----
    gemm_tile(tile, node, c0, W2, b2, r);
#pragma unroll
    for (int c = 0; c < 32; ++c) r[c] = elu_f(r[c]);
    __syncthreads();
#pragma unroll
    for (int c = 0; c < 32; ++c) tile[node][c0 + c] = __float2half(r[c]);
    __syncthreads();

    if (!POOL) {
        // coalesced fp16 write of h
        __half2* hout2 = reinterpret_cast<__half2*>(hout);
        for (int idx = t; idx < 64 * 64; idx += 256) {
            int n = idx >> 6, c2 = idx & 63;
            hout2[(size_t)(base + n) * 64 + c2] =
                *reinterpret_cast<const __half2*>(&tile[n][2 * c2]);
        }
    } else {
        // per-block partial max per graph segment, then one atomic per (graph,col)
        if (t < DIM) {
            const int col = t;
            const int g0 = batch_s[0], g1 = batch_s[63];
            for (int g = g0; g <= g1; ++g) {
                float m = -INFINITY;
                bool any = false;
                for (int i = 0; i < 64; ++i) {
                    if (batch_s[i] == g) { m = fmaxf(m, __half2float(tile[i][col])); any = true; }
                }
                if (any) atomicMax(&gkey[(size_t)g * DIM + col], enc_f(m));
            }
        }
    }
}

// ---------------- head ----------------

__global__ __launch_bounds__(128) void head_kernel(const unsigned int* __restrict__ gkey,
                                                   const float* __restrict__ l1W,
                                                   const float* __restrict__ l1b,
                                                   const float* __restrict__ l2W,
                                                   const float* __restrict__ l2b,
                                                   float* __restrict__ out) {
    __shared__ float gv[DIM];
    __shared__ float y1[DIM];
    __shared__ float lg[NC];
    const int g = blockIdx.x;
    const int t = threadIdx.x;
    gv[t] = dec_f(gkey[(size_t)g * DIM + t]);
    __syncthreads();
    float s = l1b[t];
    for (int k = 0; k < DIM; ++k) s += gv[k] * l1W[k * DIM + t];
    y1[t] = elu_f(s);
    __syncthreads();
    if (t < NC) {
        float s2 = l2b[t];
        for (int k = 0; k < DIM; ++k) s2 += y1[k] * l2W[k * NC + t];
        lg[t] = s2;
    }
    __syncthreads();
    if (t == 0) {
        float m = -INFINITY;
        for (int j = 0; j < NC; ++j) m = fmaxf(m, lg[j]);
        float e[NC];
        float sum = 0.f;
        for (int j = 0; j < NC; ++j) { e[j] = expf(lg[j] - m); sum += e[j]; }
        float inv = 1.f / sum;
        for (int j = 0; j < NC; ++j) out[(size_t)g * NC + j] = e[j] * inv;
    }
}

// ---------------- launch ----------------

extern "C" void kernel_launch(void* const* d_in, const int* in_sizes, int n_in,
                              void* d_out, int out_size, void* d_ws, size_t ws_size,
                              hipStream_t stream) {
    (void)in_sizes; (void)n_in; (void)out_size; (void)ws_size;
    const float* x     = (const float*)d_in[0];
    const int*   edge  = (const int*)d_in[1];
    const int*   batch = (const int*)d_in[2];
    const float* c1_W1 = (const float*)d_in[3];
    const float* c1_b1 = (const float*)d_in[4];
    const float* c1_g  = (const float*)d_in[5];
    const float* c1_be = (const float*)d_in[6];
    const float* c1_rm = (const float*)d_in[7];
    const float* c1_rv = (const float*)d_in[8];
    const float* c1_W2 = (const float*)d_in[9];
    const float* c1_b2 = (const float*)d_in[10];
    const float* c2_W1 = (const float*)d_in[11];
    const float* c2_b1 = (const float*)d_in[12];
    const float* c2_g  = (const float*)d_in[13];
    const float* c2_be = (const float*)d_in[14];
    const float* c2_rm = (const float*)d_in[15];
    const float* c2_rv = (const float*)d_in[16];
    const float* c2_W2 = (const float*)d_in[17];
    const float* c2_b2 = (const float*)d_in[18];
    const float* l1_W  = (const float*)d_in[19];
    const float* l1_b  = (const float*)d_in[20];
    const float* l2_W  = (const float*)d_in[21];
    const float* l2_b  = (const float*)d_in[22];
    float* out = (float*)d_out;

    char* wsb = (char*)d_ws;
    size_t off = 0;
    auto take = [&](size_t bytes) -> char* {
        char* p = wsb + off;
        off += (bytes + 255) & ~(size_t)255;
        return p;
    };
    int* counts    = (int*)take((size_t)NN * 4);
    int* offs      = (int*)take((size_t)(NN + 1) * 4);
    int* cursor    = (int*)take((size_t)NN * 4);
    int* bsum      = (int*)take(256 * 4);
    int* bscan     = (int*)take(256 * 4);
    int* csr       = (int*)take((size_t)NE_PAD * 4);
    __half* xh     = (__half*)take((size_t)(NN + 1) * DIM * 2);   // +1: zero pad row
    __half* h1h    = (__half*)take((size_t)(NN + 1) * DIM * 2);
    unsigned* gkey = (unsigned*)take((size_t)NG * DIM * 4);
    float* W1f_a   = (float*)take((size_t)DIM * DIM * 4);
    float* b1f_a   = (float*)take((size_t)DIM * 4);
    float* W1f_b   = (float*)take((size_t)DIM * DIM * 4);
    float* b1f_b   = (float*)take((size_t)DIM * 4);

    const int* esrc = edge;
    const int* edst = edge + NE;

    hipMemsetAsync(counts, 0, (size_t)NN * 4, stream);
    hipMemsetAsync(gkey, 0, (size_t)NG * DIM * 4, stream);
    // zero the dummy pad rows (ws is poisoned before every call)
    hipMemsetAsync(xh + (size_t)NN * DIM, 0, DIM * 2, stream);
    hipMemsetAsync(h1h + (size_t)NN * DIM, 0, DIM * 2, stream);

    fold_kernel<<<64, 256, 0, stream>>>(c1_W1, c1_b1, c1_g, c1_be, c1_rm, c1_rv, W1f_a, b1f_a);
    fold_kernel<<<64, 256, 0, stream>>>(c2_W1, c2_b1, c2_g, c2_be, c2_rm, c2_rv, W1f_b, b1f_b);

    to_half_kernel<<<2048, 256, 0, stream>>>(x, xh, NN * DIM / 2);

    hist_kernel<<<4096, 256, 0, stream>>>(edst, counts);
    pad_counts_kernel<<<782, 256, 0, stream>>>(counts);
    scan_block_kernel<<<196, 1024, 0, stream>>>(counts, offs, bsum);
    scan_bsum_kernel<<<1, 1, 0, stream>>>(bsum, bscan, 196, offs);
    add_bscan_kernel<<<782, 256, 0, stream>>>(offs, bscan, cursor);
    csr_init_kernel<<<4096, 256, 0, stream>>>(csr);
    fill_kernel<<<4096, 256, 0, stream>>>(esrc, edst, cursor, csr);

    gin_layer_kernel<0><<<NN / 64, 256, 0, stream>>>(xh, offs, csr, W1f_a, b1f_a, c1_W2, c1_b2,
                                                     h1h, nullptr, nullptr);
    gin_layer_kernel<1><<<NN / 64, 256, 0, stream>>>(h1h, offs, csr, W1f_b, b1f_b, c2_W2, c2_b2,
                                                     nullptr, gkey, batch);

    head_kernel<<<NG, 128, 0, stream>>>(gkey, l1_W, l1_b, l2_W, l2_b, out);
}